// Round 5
// baseline (52.798 us; speedup 1.0000x reference)
//
#include <hip/hip_runtime.h>
#include <cmath>

// Problem constants (match the reference)
#define HH 256
#define WW 256
#define NG 1024
#define NB 2
static constexpr float FXc = 300.0f;
static constexpr float FYc = 300.0f;
static constexpr float CXc = 128.0f;
static constexpr float CYc = 128.0f;
static constexpr float EPSc = 1e-8f;
static constexpr float LOG2E = 1.4426950408889634f;

#if defined(__has_builtin)
#if __has_builtin(__builtin_amdgcn_exp2f)
#define FAST_EXP2(x) __builtin_amdgcn_exp2f(x)
#else
#define FAST_EXP2(x) exp2f(x)
#endif
#else
#define FAST_EXP2(x) exp2f(x)
#endif

// Layout:
//   grid = 1024 blocks (NB * 512), 256 threads, 32x4-px tile per block.
//   Thread = (oct t [0,16), h [0,16)).  Each thread: 4x2 pixel oct,
//   gaussians g = i*16 + h (i in [0,64)) -> 16-way split, reduce-scatter.
//   Weights inside the oct via multiplicative walk: 3 exp + 9 mul per
//   gaussian-oct instead of 8 exp (e-deltas are linear; 2nd diff = 2k,
//   y-delta independent of x).
//   NaN guard: step deltas clamped to <=126 so far-off-screen gaussians
//   (w00 flushed to 0) never produce 0*inf. Clamp is lossless: slope at
//   any non-flushed weight is < 3.8 log2/px (|k| <= 0.029).
__global__ __launch_bounds__(256) void render_kernel(
    const float* __restrict__ positions,   // [N,3]
    const float* __restrict__ colors,      // [N,3]
    const float* __restrict__ opacities,   // [N,1]
    const float* __restrict__ scales,      // [N,1]
    const float* __restrict__ qvec,        // [B,4]
    const float* __restrict__ tvec,        // [B,3]
    float* __restrict__ out)               // [B,3,H,W]
{
    __shared__ float4 gs0[NG];  // (k, kx, ky, A)  A = k*|u|^2 + log2(op)
    __shared__ float4 gs1[NG];  // (r, g, b, G = 2^(2k))

    const int b = blockIdx.x >> 9;          // 512 blocks per batch
    const int tile = blockIdx.x & 511;
    const int x0 = (tile & 7) << 5;         // 8 tiles of 32 px in x
    const int y0 = (tile >> 3) << 2;        // 64 tiles of 4 px in y

    // --- per-thread (wave-uniform) rotation setup ---
    float qw = qvec[b * 4 + 0], qx = qvec[b * 4 + 1];
    float qy = qvec[b * 4 + 2], qz = qvec[b * 4 + 3];
    float rin = rsqrtf(qw * qw + qx * qx + qy * qy + qz * qz);
    qw *= rin; qx *= rin; qy *= rin; qz *= rin;
    const float r00 = 1.0f - 2.0f * (qy * qy + qz * qz);
    const float r01 = 2.0f * (qx * qy - qz * qw);
    const float r02 = 2.0f * (qx * qz + qy * qw);
    const float r10 = 2.0f * (qx * qy + qz * qw);
    const float r11 = 1.0f - 2.0f * (qx * qx + qz * qz);
    const float r12 = 2.0f * (qy * qz - qx * qw);
    const float r20 = 2.0f * (qx * qz - qy * qw);
    const float r21 = 2.0f * (qy * qz + qx * qw);
    const float r22 = 1.0f - 2.0f * (qx * qx + qy * qy);
    const float t0 = tvec[b * 3 + 0], t1 = tvec[b * 3 + 1], t2 = tvec[b * 3 + 2];

    // --- stage all N gaussians into LDS (each thread projects 4) ---
    #pragma unroll
    for (int j = 0; j < NG / 256; ++j) {
        const int g = threadIdx.x + j * 256;
        const float X = positions[g * 3 + 0];
        const float Y = positions[g * 3 + 1];
        const float Z = positions[g * 3 + 2];
        const float cxp = r00 * X + r01 * Y + r02 * Z + t0;
        const float cyp = r10 * X + r11 * Y + r12 * Z + t1;
        const float czp = r20 * X + r21 * Y + r22 * Z + t2;
        const float iz = 1.0f / czp;
        const float ux = cxp * iz * FXc + CXc;
        const float uy = cyp * iz * FYc + CYc;
        const float s = scales[g];
        const float k = -0.5f * LOG2E / (s * s);
        const float lop = __log2f(opacities[g]);
        const float kx = -2.0f * k * ux;
        const float ky = -2.0f * k * uy;
        const float A = fmaf(k, fmaf(ux, ux, uy * uy), lop);
        gs0[g] = make_float4(k, kx, ky, A);
        gs1[g] = make_float4(colors[g * 3 + 0], colors[g * 3 + 1],
                             colors[g * 3 + 2], exp2f(2.0f * k));
    }
    __syncthreads();

    // --- oct / split decomposition ---
    const int h = threadIdx.x & 15;         // gaussian split lane
    const int t = threadIdx.x >> 4;         // oct id [0,16)
    const int ox = x0 + ((t & 7) << 2);     // oct base x (4 px wide)
    const int oy = y0 + ((t >> 3) << 1);    // oct base y (2 px tall)
    const float px = (float)ox;
    const float py = (float)oy;
    const float c2 = fmaf(px, px, py * py);
    const float u = fmaf(2.0f, px, 1.0f);
    const float v = fmaf(2.0f, py, 1.0f);

    // acc[v]: v = p*4 + ch, p = x + 4*y (4x2 oct), ch: 0=den,1=r,2=g,3=b
    float acc[32];
    #pragma unroll
    for (int i = 0; i < 32; ++i) acc[i] = 0.0f;

    #pragma unroll 2
    for (int i = 0; i < NG / 16; ++i) {
        const int g = (i << 4) + h;
        const float4 g0 = gs0[g];
        const float4 g1 = gs1[g];
        const float k = g0.x;
        float e00 = fmaf(k, c2, g0.w);
        e00 = fmaf(g0.y, px, e00);
        e00 = fmaf(g0.z, py, e00);
        // step deltas, clamped so exp2 stays finite (see header comment)
        const float d10 = fminf(fmaf(k, u, g0.y), 126.0f);
        const float d01 = fminf(fmaf(k, v, g0.z), 126.0f);
        float Ex = FAST_EXP2(d10);
        const float Ey = FAST_EXP2(d01);
        const float G = g1.w;                // 2^(2k): per-step ratio growth
        float w[8];
        w[0] = FAST_EXP2(e00);
        w[1] = w[0] * Ex;
        Ex *= G;
        w[2] = w[1] * Ex;
        Ex *= G;
        w[3] = w[2] * Ex;
        w[4] = w[0] * Ey;
        w[5] = w[1] * Ey;
        w[6] = w[2] * Ey;
        w[7] = w[3] * Ey;
        #pragma unroll
        for (int p = 0; p < 8; ++p) {
            acc[p * 4 + 0] += w[p];
            acc[p * 4 + 1] = fmaf(w[p], g1.x, acc[p * 4 + 1]);
            acc[p * 4 + 2] = fmaf(w[p], g1.y, acc[p * 4 + 2]);
            acc[p * 4 + 3] = fmaf(w[p], g1.z, acc[p * 4 + 3]);
        }
    }

    // --- butterfly reduce-scatter over the 16-lane split group ---
    // After stage st (m=1<<st, H=16>>st), active array is acc[0..H).
    #pragma unroll
    for (int st = 0; st < 4; ++st) {
        const int m = 1 << st;
        const int H = 16 >> st;
        const bool hi = (h & m) != 0;
        #pragma unroll
        for (int j = 0; j < H; ++j) {
            const float send = hi ? acc[j] : acc[j + H];
            const float keep = hi ? acc[j + H] : acc[j];
            acc[j] = keep + __shfl_xor(send, m);
        }
    }

    // lane h owns original slots v0, v0+1:
    // v0 = 16*bit0(h) + 8*bit1(h) + 4*bit2(h) + 2*bit3(h)
    const int v0 = ((h & 1) << 4) | ((h & 2) << 2) | (h & 4) | ((h & 8) >> 2);
    const int p = v0 >> 2;                  // pixel slot 0..7
    const bool gb = (v0 & 2) != 0;          // holds (g,b)? else (den,r)
    const float denOther = __shfl_xor(acc[0], 8);  // partner flips v0 bit1
    const float den = gb ? denOther : acc[0];
    const float inv = 1.0f / (den + EPSc);
    const int pxx = ox + (p & 3);
    const int pyy = oy + (p >> 2);
    const size_t o = (size_t)b * 3 * 65536 + (size_t)pyy * WW + pxx;
    if (gb) {
        out[o + 65536]  = acc[0] * inv;     // g
        out[o + 131072] = acc[1] * inv;     // b
    } else {
        out[o] = acc[1] * inv;              // r
    }
}

extern "C" void kernel_launch(void* const* d_in, const int* in_sizes, int n_in,
                              void* d_out, int out_size, void* d_ws, size_t ws_size,
                              hipStream_t stream) {
    const float* positions = (const float*)d_in[0];
    const float* colors    = (const float*)d_in[1];
    const float* opacities = (const float*)d_in[2];
    const float* scales    = (const float*)d_in[3];
    const float* qvec      = (const float*)d_in[4];
    const float* tvec      = (const float*)d_in[5];
    float* out = (float*)d_out;

    render_kernel<<<dim3(NB * 512), dim3(256), 0, stream>>>(
        positions, colors, opacities, scales, qvec, tvec, out);
}

// Round 6
// 34.516 us; speedup vs baseline: 1.5296x; 1.5296x over previous
//
#include <hip/hip_runtime.h>
#include <cmath>

// Problem constants (match the reference)
#define HH 256
#define WW 256
#define NG 1024
#define NB 2
static constexpr float FXc = 300.0f;
static constexpr float FYc = 300.0f;
static constexpr float CXc = 128.0f;
static constexpr float CYc = 128.0f;
static constexpr float EPSc = 1e-8f;
static constexpr float LOG2E = 1.4426950408889634f;

#if defined(__has_builtin)
#if __has_builtin(__builtin_amdgcn_exp2f)
#define FAST_EXP2(x) __builtin_amdgcn_exp2f(x)
#else
#define FAST_EXP2(x) exp2f(x)
#endif
#else
#define FAST_EXP2(x) exp2f(x)
#endif

// Layout (R3 skeleton, occupancy-doubled):
//   grid = 512 blocks (NB * 256), 512 threads, 32x8-px tile per block.
//   Thread = (quad t [0,64), h [0,8)).  Each thread: 2x2 pixel quad,
//   gaussians g = i*8 + h (i in [0,128)) -> 8-way split, shfl_xor combine.
//   Per gaussian-quad: 3 exp (w00, Ex=2^d10, Ey=2^d01) + 3 mul instead of
//   4 exp; step deltas clamped <=126 so flushed-to-zero far gaussians never
//   produce 0*inf (clamp engages only where w00==0; lossless).
//   LDS: split 16B-stride arrays -> zero ds_read_b128 bank conflicts.
//   Occupancy: 32KB LDS, 512 thr -> 4 blocks/CU ceiling (32 waves/CU).
__global__ __launch_bounds__(512) void render_kernel(
    const float* __restrict__ positions,   // [N,3]
    const float* __restrict__ colors,      // [N,3]
    const float* __restrict__ opacities,   // [N,1]
    const float* __restrict__ scales,      // [N,1]
    const float* __restrict__ qvec,        // [B,4]
    const float* __restrict__ tvec,        // [B,3]
    float* __restrict__ out)               // [B,3,H,W]
{
    __shared__ float4 gs0[NG];  // (k, kx, ky, A)  A = k*|u|^2 + log2(op)
    __shared__ float4 gs1[NG];  // (r, g, b, 0)

    const int b = blockIdx.x >> 8;          // 256 blocks per batch
    const int tile = blockIdx.x & 255;
    const int x0 = (tile & 7) << 5;         // 8 tiles of 32 px in x
    const int y0 = (tile >> 3) << 3;        // 32 tiles of 8 px in y

    // --- per-thread (wave-uniform) rotation setup ---
    float qw = qvec[b * 4 + 0], qx = qvec[b * 4 + 1];
    float qy = qvec[b * 4 + 2], qz = qvec[b * 4 + 3];
    float rin = rsqrtf(qw * qw + qx * qx + qy * qy + qz * qz);
    qw *= rin; qx *= rin; qy *= rin; qz *= rin;
    const float r00 = 1.0f - 2.0f * (qy * qy + qz * qz);
    const float r01 = 2.0f * (qx * qy - qz * qw);
    const float r02 = 2.0f * (qx * qz + qy * qw);
    const float r10 = 2.0f * (qx * qy + qz * qw);
    const float r11 = 1.0f - 2.0f * (qx * qx + qz * qz);
    const float r12 = 2.0f * (qy * qz - qx * qw);
    const float r20 = 2.0f * (qx * qz - qy * qw);
    const float r21 = 2.0f * (qy * qz + qx * qw);
    const float r22 = 1.0f - 2.0f * (qx * qx + qy * qy);
    const float t0 = tvec[b * 3 + 0], t1 = tvec[b * 3 + 1], t2 = tvec[b * 3 + 2];

    // --- stage all N gaussians into LDS (each thread projects 2) ---
    #pragma unroll
    for (int j = 0; j < NG / 512; ++j) {
        const int g = threadIdx.x + j * 512;
        const float X = positions[g * 3 + 0];
        const float Y = positions[g * 3 + 1];
        const float Z = positions[g * 3 + 2];
        const float cxp = r00 * X + r01 * Y + r02 * Z + t0;
        const float cyp = r10 * X + r11 * Y + r12 * Z + t1;
        const float czp = r20 * X + r21 * Y + r22 * Z + t2;
        const float iz = 1.0f / czp;
        const float ux = cxp * iz * FXc + CXc;
        const float uy = cyp * iz * FYc + CYc;
        const float s = scales[g];
        const float k = -0.5f * LOG2E / (s * s);
        const float lop = __log2f(opacities[g]);
        const float kx = -2.0f * k * ux;
        const float ky = -2.0f * k * uy;
        const float A = fmaf(k, fmaf(ux, ux, uy * uy), lop);
        gs0[g] = make_float4(k, kx, ky, A);
        gs1[g] = make_float4(colors[g * 3 + 0], colors[g * 3 + 1],
                             colors[g * 3 + 2], 0.0f);
    }
    __syncthreads();

    // --- quad / split decomposition ---
    const int h = threadIdx.x & 7;          // gaussian split lane
    const int t = threadIdx.x >> 3;         // quad id [0,64)
    const int px0i = x0 + ((t & 15) << 1);  // 16 quads in x
    const int py0i = y0 + ((t >> 4) << 1);  // 4 quads in y
    const float px = (float)px0i;
    const float py = (float)py0i;
    const float c2 = fmaf(px, px, py * py);
    const float u = fmaf(2.0f, px, 1.0f);   // c2(x+1)-c2(x)
    const float v = fmaf(2.0f, py, 1.0f);   // c2(y+1)-c2(y)

    // accumulators: component x=(0,0), y=(+1,0), z=(0,+1), w=(+1,+1)
    float4 aden = make_float4(0.f, 0.f, 0.f, 0.f);
    float4 ar = aden, ag = aden, ab = aden;

    #pragma unroll 4
    for (int i = 0; i < NG / 8; ++i) {
        const int g = (i << 3) + h;
        const float4 g0 = gs0[g];
        const float4 g1 = gs1[g];
        const float k = g0.x;
        float e00 = fmaf(k, c2, g0.w);
        e00 = fmaf(g0.y, px, e00);
        e00 = fmaf(g0.z, py, e00);
        const float d10 = fminf(fmaf(k, u, g0.y), 126.0f);  // e(x+1)-e(x)
        const float d01 = fminf(fmaf(k, v, g0.z), 126.0f);  // e(y+1)-e(y)
        const float w00 = FAST_EXP2(e00);
        const float Ex = FAST_EXP2(d10);
        const float Ey = FAST_EXP2(d01);
        const float w10 = w00 * Ex;
        const float w01 = w00 * Ey;
        const float w11 = w10 * Ey;
        aden.x += w00; aden.y += w10; aden.z += w01; aden.w += w11;
        ar.x = fmaf(w00, g1.x, ar.x); ar.y = fmaf(w10, g1.x, ar.y);
        ar.z = fmaf(w01, g1.x, ar.z); ar.w = fmaf(w11, g1.x, ar.w);
        ag.x = fmaf(w00, g1.y, ag.x); ag.y = fmaf(w10, g1.y, ag.y);
        ag.z = fmaf(w01, g1.y, ag.z); ag.w = fmaf(w11, g1.y, ag.w);
        ab.x = fmaf(w00, g1.z, ab.x); ab.y = fmaf(w10, g1.z, ab.y);
        ab.z = fmaf(w01, g1.z, ab.z); ab.w = fmaf(w11, g1.z, ab.w);
    }

    // --- butterfly combine across the 8-lane split group ---
    #pragma unroll
    for (int m = 1; m <= 4; m <<= 1) {
        aden.x += __shfl_xor(aden.x, m); aden.y += __shfl_xor(aden.y, m);
        aden.z += __shfl_xor(aden.z, m); aden.w += __shfl_xor(aden.w, m);
        ar.x += __shfl_xor(ar.x, m); ar.y += __shfl_xor(ar.y, m);
        ar.z += __shfl_xor(ar.z, m); ar.w += __shfl_xor(ar.w, m);
        ag.x += __shfl_xor(ag.x, m); ag.y += __shfl_xor(ag.y, m);
        ag.z += __shfl_xor(ag.z, m); ag.w += __shfl_xor(ag.w, m);
        ab.x += __shfl_xor(ab.x, m); ab.y += __shfl_xor(ab.y, m);
        ab.z += __shfl_xor(ab.z, m); ab.w += __shfl_xor(ab.w, m);
    }

    // --- epilogue: lanes h<4 each write one pixel of the quad ---
    if (h < 4) {
        float den, cr, cg, cb;
        if (h == 0)      { den = aden.x; cr = ar.x; cg = ag.x; cb = ab.x; }
        else if (h == 1) { den = aden.y; cr = ar.y; cg = ag.y; cb = ab.y; }
        else if (h == 2) { den = aden.z; cr = ar.z; cg = ag.z; cb = ab.z; }
        else             { den = aden.w; cr = ar.w; cg = ag.w; cb = ab.w; }
        const int pxx = px0i + (h & 1);
        const int pyy = py0i + (h >> 1);
        const float inv = 1.0f / (den + EPSc);
        const size_t o = (size_t)b * 3 * 65536 + (size_t)pyy * WW + pxx;
        out[o]           = cr * inv;
        out[o + 65536]   = cg * inv;
        out[o + 131072]  = cb * inv;
    }
}

extern "C" void kernel_launch(void* const* d_in, const int* in_sizes, int n_in,
                              void* d_out, int out_size, void* d_ws, size_t ws_size,
                              hipStream_t stream) {
    const float* positions = (const float*)d_in[0];
    const float* colors    = (const float*)d_in[1];
    const float* opacities = (const float*)d_in[2];
    const float* scales    = (const float*)d_in[3];
    const float* qvec      = (const float*)d_in[4];
    const float* tvec      = (const float*)d_in[5];
    float* out = (float*)d_out;

    render_kernel<<<dim3(NB * 256), dim3(512), 0, stream>>>(
        positions, colors, opacities, scales, qvec, tvec, out);
}